// Round 5
// baseline (623.827 us; speedup 1.0000x reference)
//
#include <hip/hip_runtime.h>
#include <hip/hip_bf16.h>

// sLSTM block, MI355X. One fused bf16 MFMA GEMM
//   P[g] = [x|h] (4096x4096) @ [Wg|Rg]^T (2048x4096), g in {z,i,f,o}
// with gating epilogue fused (LDS exchange of the 4 gate tiles).
// R8: R3's proven multi-block structure (128x256 tile, 8 waves, 48KB LDS,
//     3 blocks/CU, 2 syncthreads/K-step) + 32x32x16 MFMA (-17% MFMA pipe,
//     half the MFMA instr count) + k-panel global layout so staging is
//     contiguous and all ds_read_b128 are conflict-free without swizzle.
// Workspace (k-panel layout, 16B chunks of 8 bf16):
//   A_p [512 kc][4096 row][8]  @0      (32MB)
//   W_p [512 kc][8192 grow][8] @32MB   (64MB)   grow = gate*2048 + j
//   Bb  fp32 [4][2048]         @96MB

#define BATCH 4096
#define NHID  2048
#define KDIM  4096
#define NTOT  8388608L   // BATCH*NHID
#define AW_OFS 16777216  // ushort elements from A_p base to W_p base

typedef float  f32x4   __attribute__((ext_vector_type(4)));
typedef float  f32x16  __attribute__((ext_vector_type(16)));
typedef short  short8  __attribute__((ext_vector_type(8)));
typedef unsigned short ushort8 __attribute__((ext_vector_type(8)));

#define GL_LDS16(gp, lp)                                                      \
    __builtin_amdgcn_global_load_lds(                                         \
        (const __attribute__((address_space(1))) void*)(gp),                  \
        (__attribute__((address_space(3))) void*)(lp), 16, 0, 0)

__device__ __forceinline__ unsigned short f2bf(float f) {
    unsigned u = __float_as_uint(f);
    unsigned r = (u + 0x7fffu + ((u >> 16) & 1u)) >> 16;   // RNE
    return (unsigned short)r;
}

// ---- fp32 -> bf16 k-panel pack of A = [x | h_prev] ------------------------
// Block: 32 rows x 64 k (8 chunks). LDS-transposed so global writes are
// contiguous 512B runs. grid (128 row-tiles, 64 k-tiles) x 256 thr.
__global__ void convA_kernel(const float* __restrict__ x,
                             const float* __restrict__ h,
                             unsigned short* __restrict__ Ap) {
    __shared__ unsigned short tile[8][32][8];
    const int t  = threadIdx.x;
    const int r  = t >> 3, c8 = t & 7;
    const int row = blockIdx.x * 32 + r;
    const int k0  = blockIdx.y * 64;
    const float* src = (blockIdx.y < 32)
        ? (x + (long)row * 2048 + k0 + c8 * 8)
        : (h + (long)row * 2048 + (k0 - 2048) + c8 * 8);
    f32x4 v0 = __builtin_nontemporal_load((const f32x4*)src);
    f32x4 v1 = __builtin_nontemporal_load((const f32x4*)src + 1);
    ushort8 o;
    o[0] = f2bf(v0[0]); o[1] = f2bf(v0[1]); o[2] = f2bf(v0[2]); o[3] = f2bf(v0[3]);
    o[4] = f2bf(v1[0]); o[5] = f2bf(v1[1]); o[6] = f2bf(v1[2]); o[7] = f2bf(v1[3]);
    *(ushort8*)&tile[c8][(r ^ (c8 << 2)) & 31][0] = o;   // XOR-swz: no bank conflict
    __syncthreads();
    const int kcl = t >> 5, rr = t & 31;
    ushort8 w = *(ushort8*)&tile[kcl][(rr ^ (kcl << 2)) & 31][0];
    long dst = ((long)(blockIdx.y * 8 + kcl) * 4096 + blockIdx.x * 32 + rr) * 8;
    __builtin_nontemporal_store(w, (ushort8*)(Ap + dst));
}

// ---- fp32 -> bf16 k-panel pack of W_p ------------------------------------
// z = blockIdx.z: 0..3 = Wzx..Wox (k<2048), 4..7 = Rzh..Roh (k>=2048).
// grid (64 j-tiles of 32, 32 k2-tiles of 64, 8) x 256 thr.
__global__ void convW_kernel(const float* __restrict__ w0, const float* __restrict__ w1,
                             const float* __restrict__ w2, const float* __restrict__ w3,
                             const float* __restrict__ w4, const float* __restrict__ w5,
                             const float* __restrict__ w6, const float* __restrict__ w7,
                             unsigned short* __restrict__ Wp) {
    __shared__ unsigned short tile[8][32][8];
    const int z = blockIdx.z;
    const float* src;
    switch (z) {
        case 0: src = w0; break; case 1: src = w1; break;
        case 2: src = w2; break; case 3: src = w3; break;
        case 4: src = w4; break; case 5: src = w5; break;
        case 6: src = w6; break; default: src = w7; break;
    }
    const int g = z & 3, hf = z >> 2;
    const int t = threadIdx.x;
    const int r = t >> 3, c8 = t & 7;
    const int j  = blockIdx.x * 32 + r;
    const int k2 = blockIdx.y * 64 + c8 * 8;
    const float* p = src + (long)j * 2048 + k2;
    f32x4 v0 = __builtin_nontemporal_load((const f32x4*)p);
    f32x4 v1 = __builtin_nontemporal_load((const f32x4*)p + 1);
    ushort8 o;
    o[0] = f2bf(v0[0]); o[1] = f2bf(v0[1]); o[2] = f2bf(v0[2]); o[3] = f2bf(v0[3]);
    o[4] = f2bf(v1[0]); o[5] = f2bf(v1[1]); o[6] = f2bf(v1[2]); o[7] = f2bf(v1[3]);
    *(ushort8*)&tile[c8][(r ^ (c8 << 2)) & 31][0] = o;
    __syncthreads();
    const int kcl = t >> 5, rr = t & 31;
    ushort8 w = *(ushort8*)&tile[kcl][(rr ^ (kcl << 2)) & 31][0];
    const int kcg = hf * 256 + blockIdx.y * 8 + kcl;
    long dst = ((long)kcg * 8192 + g * 2048 + blockIdx.x * 32 + rr) * 8;
    __builtin_nontemporal_store(w, (ushort8*)(Wp + dst));
}

// ---- combined bias Bb[g][j] = Wg_b[j] + Rg_b[j] ---------------------------
__global__ void bias_kernel(const float* __restrict__ b0, const float* __restrict__ b1,
                            const float* __restrict__ b2, const float* __restrict__ b3,
                            const float* __restrict__ r0, const float* __restrict__ r1,
                            const float* __restrict__ r2, const float* __restrict__ r3,
                            float* __restrict__ Bb) {
    int gid = blockIdx.x * 256 + threadIdx.x;        // 0..8191
    int g = gid >> 11, j = gid & 2047;
    const float *wb, *rb;
    switch (g) {
        case 0: wb = b0; rb = r0; break; case 1: wb = b1; rb = r1; break;
        case 2: wb = b2; rb = r2; break; default: wb = b3; rb = r3; break;
    }
    Bb[gid] = wb[j] + rb[j];
}

// ---- fused GEMM (4 gates) + sLSTM epilogue --------------------------------
// block: 512 threads = 8 waves; wave w: gate = w&3, rowhalf rh = w>>2.
// Wave computes 64x64 of its gate as 2x2 of 32x32x16 MFMA (16 MFMA/K-tile).
// grid: (32 row-tiles of 128, 32 col-tiles of 64). LDS 48KB, 3 blocks/CU.
// LDS: As [8 kc][128 row][16B] @0 (16KB); Bs [8 kc][256 grow][16B] @16K (32KB).
// All frag reads are contiguous-512B b128 (conflict-free); staging is 48 x 1KB
// contiguous global loads into linear LDS (wave-uniform base + lane*16).
// 32x32x16 operand layout: A/B lane l holds row/col = l%32, k = (l/32)*8+e
// (extrapolated from the verified 16x16x32 pattern); C/D: col = lane&31,
// row = (reg&3) + 8*(reg>>2) + 4*(lane>>5)  [doc-verified m74/m101].
__global__ __launch_bounds__(512, 4) void slstm_kernel(
    const unsigned short* __restrict__ Ap,   // k-panel A, W follows at +AW_OFS
    const float* __restrict__ Bb,            // [4][2048]
    const float* __restrict__ c_prev,
    const float* __restrict__ n_prev,
    const float* __restrict__ m_prev,
    float* __restrict__ out)                 // h | c | n | m
{
    __shared__ uint4 smem4[49152 / 16];      // 48 KB
    char* smem = (char*)smem4;

    const int tid  = threadIdx.x;
    const int lane = tid & 63;
    const int wv   = tid >> 6;     // wave 0..7
    const int gate = wv & 3;
    const int rh   = wv >> 2;      // rowhalf 0/1 (64 rows each)
    const int l31  = lane & 31;
    const int lhi  = lane >> 5;

    const int row0 = blockIdx.x * 128;  // batch rows
    const int col0 = blockIdx.y * 64;   // hidden cols

    // fragment ds_read bases (byte offsets); + ks/mt/nt immediates later
    const int abase = lhi * 2048 + (rh * 64 + l31) * 16;            // As
    const int bbase = 16384 + lhi * 4096 + (gate * 64 + l31) * 16;  // Bs

    // staging: 48 x 1KB loads per K-tile; wave w issues ids w*6..w*6+5.
    // ids 0..15 -> As (kc = idx>>7, row = idx&127), 16..47 -> Bs (kc=idx>>8).
    int gofs[6], strd[6], lofs[6];
#pragma unroll
    for (int t = 0; t < 6; ++t) {
        int id = wv * 6 + t;
        lofs[t] = id * 1024 + lane * 16;
        if (id < 16) {
            int idx = id * 64 + lane;
            int kc = idx >> 7, row = idx & 127;
            gofs[t] = (kc * 4096 + row0 + row) * 8;
            strd[t] = 8 * 4096 * 8;            // advance 8 kc per K-tile
        } else {
            int idx = (id - 16) * 64 + lane;
            int kc = idx >> 8, gr = idx & 255;
            gofs[t] = AW_OFS + (kc * 8192 + (gr >> 6) * 2048 + col0 + (gr & 63)) * 8;
            strd[t] = 8 * 8192 * 8;
        }
    }

    f32x16 acc[2][2];
#pragma unroll
    for (int mt = 0; mt < 2; ++mt)
#pragma unroll
        for (int nt = 0; nt < 2; ++nt)
#pragma unroll
            for (int r = 0; r < 16; ++r) acc[mt][nt][r] = 0.0f;

    for (int kt = 0; kt < 64; ++kt) {
        __syncthreads();                       // everyone done reading prev tile
#pragma unroll
        for (int t = 0; t < 6; ++t) {
            GL_LDS16(Ap + gofs[t], smem + lofs[t]);
            gofs[t] += strd[t];
        }
        __syncthreads();                       // implicit vmcnt(0) drain + barrier

        __builtin_amdgcn_s_setprio(1);
#pragma unroll
        for (int ks = 0; ks < 4; ++ks) {       // k = kt*64 + ks*16
            short8 a0 = *(const short8*)(smem + abase + ks * 4096);
            short8 a1 = *(const short8*)(smem + abase + ks * 4096 + 512);
            short8 b0 = *(const short8*)(smem + bbase + ks * 8192);
            short8 b1 = *(const short8*)(smem + bbase + ks * 8192 + 512);
            acc[0][0] = __builtin_amdgcn_mfma_f32_32x32x16_bf16(a0, b0, acc[0][0], 0, 0, 0);
            acc[0][1] = __builtin_amdgcn_mfma_f32_32x32x16_bf16(a0, b1, acc[0][1], 0, 0, 0);
            acc[1][0] = __builtin_amdgcn_mfma_f32_32x32x16_bf16(a1, b0, acc[1][0], 0, 0, 0);
            acc[1][1] = __builtin_amdgcn_mfma_f32_32x32x16_bf16(a1, b1, acc[1][1], 0, 0, 0);
        }
        __builtin_amdgcn_s_setprio(0);
    }

    // ---- epilogue: 4 row-slices of 32; exchange gates via LDS -------------
    float* exch = (float*)smem;   // [4 gates][32 rows][65] floats (33.3KB)
#pragma unroll
    for (int s = 0; s < 4; ++s) {
        __syncthreads();
        if (rh == (s >> 1)) {                  // writers: mt = s&1
#pragma unroll
            for (int nt = 0; nt < 2; ++nt)
#pragma unroll
                for (int r = 0; r < 16; ++r) {
                    int lrow = (r & 3) + 8 * (r >> 2) + 4 * lhi;
                    exch[(gate * 32 + lrow) * 65 + nt * 32 + l31] = acc[s & 1][nt][r];
                }
        }
        __syncthreads();
#pragma unroll
        for (int q = 0; q < 4; ++q) {
            int e   = q * 512 + tid;          // 0..2047 = 32 rows x 64 cols
            int row = e >> 6, col = e & 63;
            int R = row0 + s * 32 + row;
            int C = col0 + col;
            long idx = (long)R * NHID + C;
            float zp = exch[(0 * 32 + row) * 65 + col] + Bb[C];
            float ip = exch[(1 * 32 + row) * 65 + col] + Bb[2048 + C];
            float fp = exch[(2 * 32 + row) * 65 + col] + Bb[4096 + C];
            float op = exch[(3 * 32 + row) * 65 + col] + Bb[6144 + C];
            float cp = __builtin_nontemporal_load(c_prev + idx);
            float np = __builtin_nontemporal_load(n_prev + idx);
            float mp = __builtin_nontemporal_load(m_prev + idx);
            float z  = tanhf(zp);
            float o  = 1.0f / (1.0f + __expf(-op));
            float mm = fmaxf(fp + mp, ip);
            float ih = __expf(ip - mm);
            float fh = __expf(fp + mp - mm);
            float cc = fh * cp + ih * z;
            float nn = fh * np + ih;
            float hh = o * cc / nn;
            __builtin_nontemporal_store(hh, out + idx);
            __builtin_nontemporal_store(cc, out + NTOT + idx);
            __builtin_nontemporal_store(nn, out + 2 * NTOT + idx);
            __builtin_nontemporal_store(mm, out + 3 * NTOT + idx);
        }
    }
}

extern "C" void kernel_launch(void* const* d_in, const int* in_sizes, int n_in,
                              void* d_out, int out_size, void* d_ws, size_t ws_size,
                              hipStream_t stream) {
    const float* x      = (const float*)d_in[0];
    const float* h_prev = (const float*)d_in[1];
    const float* c_prev = (const float*)d_in[2];
    const float* n_prev = (const float*)d_in[3];
    const float* m_prev = (const float*)d_in[4];
    unsigned short* Ap = (unsigned short*)d_ws;                          // 32 MB
    unsigned short* Wp = (unsigned short*)((char*)d_ws + 33554432);      // 64 MB
    float*          Bb = (float*)((char*)d_ws + 100663296);              // 32 KB

    convA_kernel<<<dim3(128, 64), 256, 0, stream>>>(x, h_prev, Ap);
    convW_kernel<<<dim3(64, 32, 8), 256, 0, stream>>>(
        (const float*)d_in[5], (const float*)d_in[7], (const float*)d_in[9],
        (const float*)d_in[11], (const float*)d_in[13], (const float*)d_in[15],
        (const float*)d_in[17], (const float*)d_in[19], Wp);
    bias_kernel<<<32, 256, 0, stream>>>(
        (const float*)d_in[6], (const float*)d_in[8], (const float*)d_in[10],
        (const float*)d_in[12], (const float*)d_in[14], (const float*)d_in[16],
        (const float*)d_in[18], (const float*)d_in[20], Bb);

    slstm_kernel<<<dim3(32, 32), 512, 0, stream>>>(
        Ap, Bb, c_prev, n_prev, m_prev, (float*)d_out);
}

// Round 6
// 603.357 us; speedup vs baseline: 1.0339x; 1.0339x over previous
//
#include <hip/hip_runtime.h>
#include <hip/hip_bf16.h>

// sLSTM block, MI355X. One fused bf16 MFMA GEMM
//   P[g] = [x|h] (4096x4096) @ [Wg|Rg]^T (2048x4096), g in {z,i,f,o}
// with gating epilogue fused (LDS exchange of the 4 gate tiles).
// R9 = R3 (best: 128x64x4 tile, 8 waves, 16x16x32, acc[4][4], 48KB, 3 blk/CU)
//      with ONE change: BK 64->32, double-buffered, single s_barrier per
//      K-step, per-wave vmcnt(0) of loads issued a full iteration earlier
//      (no mid-iteration drain of just-issued loads -> latency hidden
//      inside the block instead of relying on cross-block overlap).
// ws: A_bf16 [4096][4096] @0 (32MB) | Wb_bf16 [4][2048][4096] @32MB (64MB)
//     | Bb fp32 [4][2048] @96MB.

#define BATCH 4096
#define NHID  2048
#define KDIM  4096
#define NTOT  8388608L   // BATCH*NHID
#define AW_OFS 16777216  // elements from A base to W base in ws
#define BUFSZ 24576      // one stage buffer: A 8KB + B 16KB (BK=32)

typedef float  f32x4   __attribute__((ext_vector_type(4)));
typedef short  short8  __attribute__((ext_vector_type(8)));
typedef unsigned short ushort8 __attribute__((ext_vector_type(8)));

#define GL_LDS16(gp, lp)                                                      \
    __builtin_amdgcn_global_load_lds(                                         \
        (const __attribute__((address_space(1))) void*)(gp),                  \
        (__attribute__((address_space(3))) void*)(lp), 16, 0, 0)

__device__ __forceinline__ unsigned short f2bf(float f) {
    unsigned u = __float_as_uint(f);
    unsigned r = (u + 0x7fffu + ((u >> 16) & 1u)) >> 16;   // RNE
    return (unsigned short)r;
}

// ---- fp32 -> bf16 pack of A = [x | h_prev], 4096 x 4096 -------------------
__global__ void convA_kernel(const float* __restrict__ x,
                             const float* __restrict__ h,
                             unsigned short* __restrict__ A) {
    int gid = blockIdx.x * 256 + threadIdx.x;       // 4096*512 groups of 8
    int row = gid >> 9;
    int col = (gid & 511) << 3;
    const float* src = (col < 2048) ? (x + (long)row * 2048 + col)
                                    : (h + (long)row * 2048 + (col - 2048));
    f32x4 v0 = __builtin_nontemporal_load((const f32x4*)src);
    f32x4 v1 = __builtin_nontemporal_load((const f32x4*)src + 1);
    ushort8 o;
    o[0] = f2bf(v0[0]); o[1] = f2bf(v0[1]); o[2] = f2bf(v0[2]); o[3] = f2bf(v0[3]);
    o[4] = f2bf(v1[0]); o[5] = f2bf(v1[1]); o[6] = f2bf(v1[2]); o[7] = f2bf(v1[3]);
    *(ushort8*)(A + ((long)row << 12) + col) = o;
}

// ---- fp32 -> bf16 pack of Wb[g][j][k] (k<2048: Wg, k>=2048: Rg) -----------
__global__ void convW_kernel(const float* __restrict__ w0, const float* __restrict__ w1,
                             const float* __restrict__ w2, const float* __restrict__ w3,
                             const float* __restrict__ w4, const float* __restrict__ w5,
                             const float* __restrict__ w6, const float* __restrict__ w7,
                             unsigned short* __restrict__ Wb) {
    int z = blockIdx.y;                              // 0..3 = Wzx..Wox, 4..7 = Rzh..Roh
    const float* src;
    switch (z) {
        case 0: src = w0; break; case 1: src = w1; break;
        case 2: src = w2; break; case 3: src = w3; break;
        case 4: src = w4; break; case 5: src = w5; break;
        case 6: src = w6; break; default: src = w7; break;
    }
    int gid = blockIdx.x * 256 + threadIdx.x;        // 2048*256 groups of 8
    int row = gid >> 8;
    int col = (gid & 255) << 3;
    const float* p = src + (long)row * 2048 + col;
    f32x4 v0 = __builtin_nontemporal_load((const f32x4*)p);
    f32x4 v1 = __builtin_nontemporal_load((const f32x4*)p + 1);
    ushort8 o;
    o[0] = f2bf(v0[0]); o[1] = f2bf(v0[1]); o[2] = f2bf(v0[2]); o[3] = f2bf(v0[3]);
    o[4] = f2bf(v1[0]); o[5] = f2bf(v1[1]); o[6] = f2bf(v1[2]); o[7] = f2bf(v1[3]);
    int g = z & 3, hf = z >> 2;
    *(ushort8*)(Wb + (long)g * NHID * KDIM + (long)row * KDIM + hf * 2048 + col) = o;
}

// ---- combined bias Bb[g][j] = Wg_b[j] + Rg_b[j] ---------------------------
__global__ void bias_kernel(const float* __restrict__ b0, const float* __restrict__ b1,
                            const float* __restrict__ b2, const float* __restrict__ b3,
                            const float* __restrict__ r0, const float* __restrict__ r1,
                            const float* __restrict__ r2, const float* __restrict__ r3,
                            float* __restrict__ Bb) {
    int gid = blockIdx.x * 256 + threadIdx.x;        // 0..8191
    int g = gid >> 11, j = gid & 2047;
    const float *wb, *rb;
    switch (g) {
        case 0: wb = b0; rb = r0; break; case 1: wb = b1; rb = r1; break;
        case 2: wb = b2; rb = r2; break; default: wb = b3; rb = r3; break;
    }
    Bb[gid] = wb[j] + rb[j];
}

// ---- fused GEMM (4 gates) + sLSTM epilogue --------------------------------
// block: 512 threads = 8 waves; wave w: gate = w&3, rowhalf rh = w>>2.
// Each wave computes a 64x64 tile of its gate (4x4 of 16x16x32 MFMA).
// grid: (32 row-tiles of 128, 32 col-tiles of 64); x fastest.
// LDS 48KB = 2 x 24KB buffers. Per buffer (BK=32, rows of 64B, 4 chunks):
//   A: addr(r,j)  = r*64  + (j ^ (r&3))*16,  r<128         (8KB)
//   B: 8192 + gr*64 + (j ^ (gr&3))*16,       gr=g*64+rr<256 (16KB)
// Staging: 24 x 1KB loads per K-tile (3 per wave), linear LDS dest
//   (pos idx*16 holds logical chunk jj^(r&3) -> matches layout).
// Pipeline (depth-1, single barrier per K-step):
//   iter kt: vmcnt(0) [own tile-kt loads, issued during iter kt-1]
//            s_barrier; issue stage(kt+1) -> other buffer; 8 ds_read, 16 MFMA.
__global__ __launch_bounds__(512, 4) void slstm_kernel(
    const __hip_bfloat16* __restrict__ A,    // [4096][4096], W follows at +AW_OFS
    const float* __restrict__ Bb,            // [4][2048]
    const float* __restrict__ c_prev,
    const float* __restrict__ n_prev,
    const float* __restrict__ m_prev,
    float* __restrict__ out)                 // h | c | n | m
{
    __shared__ uint4 smem4[(2 * BUFSZ) / 16];   // 48 KB -> 3 blocks/CU
    char* smem = (char*)smem4;

    const int tid  = threadIdx.x;
    const int lane = tid & 63;
    const int wv   = tid >> 6;     // wave id 0..7
    const int gate = wv & 3;
    const int rh   = wv >> 2;      // row half 0/1
    const int lm   = lane & 15;
    const int quad = lane >> 4;

    const int row0 = blockIdx.x * 128;  // batch rows
    const int col0 = blockIdx.y * 64;   // hidden cols

    // fragment ds_read bases: logical k-chunk = quad, stored at quad^(lm&3)
    const int cof   = ((quad ^ (lm & 3))) * 16;
    const int abase = (rh * 64 + lm) * 64 + cof;            // + mt*1024
    const int bbase = 8192 + (gate * 64 + lm) * 64 + cof;   // + nt*1024

    // staging: 24 loads of 1KB (64 lanes x 16B); wave w issues ids w*3..w*3+2.
    // ids 0..7 -> A tile (128 x 32), ids 8..23 -> B tiles (4 x 64 x 32).
    int gofs[3], lofs[3];
#pragma unroll
    for (int t = 0; t < 3; ++t) {
        int id = wv * 3 + t;
        if (id < 8) {
            int idx = id * 64 + lane;                // 0..511
            int r = idx >> 2, jj = idx & 3;
            int j = jj ^ (r & 3);
            gofs[t] = (row0 + r) * KDIM + j * 8;
            lofs[t] = idx * 16;
        } else {
            int idx = (id - 8) * 64 + lane;          // 0..1023
            int gr = idx >> 2, jj = idx & 3;
            int g = gr >> 6, rr = gr & 63;
            int j = jj ^ (gr & 3);
            gofs[t] = AW_OFS + (g * NHID + col0 + rr) * KDIM + j * 8;
            lofs[t] = 8192 + idx * 16;
        }
    }

    f32x4 acc[4][4];
#pragma unroll
    for (int mt = 0; mt < 4; ++mt)
#pragma unroll
        for (int nt = 0; nt < 4; ++nt)
#pragma unroll
            for (int r = 0; r < 4; ++r) acc[mt][nt][r] = 0.0f;

    // prologue: stage tile 0 -> buf0; advance offsets to tile 1
#pragma unroll
    for (int t = 0; t < 3; ++t) {
        GL_LDS16(A + gofs[t], smem + lofs[t]);
        gofs[t] += 32;
    }

    for (int kt = 0; kt < 128; ++kt) {
        // own tile-kt loads were issued during iter kt-1 (or prologue):
        // a full compute phase of slack. Retire them, then rendezvous.
        asm volatile("s_waitcnt vmcnt(0)" ::: "memory");
        __builtin_amdgcn_s_barrier();

        const char* cur = smem + (kt & 1) * BUFSZ;
        char*       wrt = smem + ((kt & 1) ^ 1) * BUFSZ;

        if (kt < 127) {
#pragma unroll
            for (int t = 0; t < 3; ++t) {
                GL_LDS16(A + gofs[t], wrt + lofs[t]);
                gofs[t] += 32;
            }
        }

        short8 af[4], bf[4];
#pragma unroll
        for (int mt = 0; mt < 4; ++mt)
            af[mt] = *(const short8*)(cur + abase + mt * 1024);
#pragma unroll
        for (int nt = 0; nt < 4; ++nt)
            bf[nt] = *(const short8*)(cur + bbase + nt * 1024);
#pragma unroll
        for (int mt = 0; mt < 4; ++mt)
#pragma unroll
            for (int nt = 0; nt < 4; ++nt)
                acc[mt][nt] = __builtin_amdgcn_mfma_f32_16x16x32_bf16(
                    af[mt], bf[nt], acc[mt][nt], 0, 0, 0);
    }

    // ---- epilogue: exchange gate tiles through LDS, compute h,c,n,m ----
    float* exch = (float*)smem;   // [2 rh][4 gates][16 rows][65] floats (33.3KB)
#pragma unroll
    for (int mt = 0; mt < 4; ++mt) {
        __syncthreads();
#pragma unroll
        for (int nt = 0; nt < 4; ++nt)
#pragma unroll
            for (int r = 0; r < 4; ++r)
                exch[((rh * 4 + gate) * 16 + quad * 4 + r) * 65 + nt * 16 + lm] =
                    acc[mt][nt][r];
        __syncthreads();
#pragma unroll
        for (int q = 0; q < 4; ++q) {
            int e   = q * 512 + tid;          // 0..2047
            int erh = e >> 10, row = (e >> 6) & 15, col = e & 63;
            int R = row0 + erh * 64 + mt * 16 + row;
            int C = col0 + col;
            long idx = (long)R * NHID + C;
            float zp = exch[((erh * 4 + 0) * 16 + row) * 65 + col] + Bb[C];
            float ip = exch[((erh * 4 + 1) * 16 + row) * 65 + col] + Bb[2048 + C];
            float fp = exch[((erh * 4 + 2) * 16 + row) * 65 + col] + Bb[4096 + C];
            float op = exch[((erh * 4 + 3) * 16 + row) * 65 + col] + Bb[6144 + C];
            float cp = __builtin_nontemporal_load(c_prev + idx);
            float np = __builtin_nontemporal_load(n_prev + idx);
            float mp = __builtin_nontemporal_load(m_prev + idx);
            float z  = tanhf(zp);
            float o  = 1.0f / (1.0f + __expf(-op));
            float mm = fmaxf(fp + mp, ip);
            float ih = __expf(ip - mm);
            float fh = __expf(fp + mp - mm);
            float cc = fh * cp + ih * z;
            float nn = fh * np + ih;
            float hh = o * cc / nn;
            __builtin_nontemporal_store(hh, out + idx);
            __builtin_nontemporal_store(cc, out + NTOT + idx);
            __builtin_nontemporal_store(nn, out + 2 * NTOT + idx);
            __builtin_nontemporal_store(mm, out + 3 * NTOT + idx);
        }
    }
}

extern "C" void kernel_launch(void* const* d_in, const int* in_sizes, int n_in,
                              void* d_out, int out_size, void* d_ws, size_t ws_size,
                              hipStream_t stream) {
    const float* x      = (const float*)d_in[0];
    const float* h_prev = (const float*)d_in[1];
    const float* c_prev = (const float*)d_in[2];
    const float* n_prev = (const float*)d_in[3];
    const float* m_prev = (const float*)d_in[4];
    unsigned short* A  = (unsigned short*)d_ws;                          // 32 MB
    unsigned short* Wb = (unsigned short*)((char*)d_ws + 33554432);      // 64 MB
    float*          Bb = (float*)((char*)d_ws + 100663296);              // 32 KB

    convA_kernel<<<8192, 256, 0, stream>>>(x, h_prev, A);
    convW_kernel<<<dim3(2048, 8), 256, 0, stream>>>(
        (const float*)d_in[5], (const float*)d_in[7], (const float*)d_in[9],
        (const float*)d_in[11], (const float*)d_in[13], (const float*)d_in[15],
        (const float*)d_in[17], (const float*)d_in[19], Wb);
    bias_kernel<<<32, 256, 0, stream>>>(
        (const float*)d_in[6], (const float*)d_in[8], (const float*)d_in[10],
        (const float*)d_in[12], (const float*)d_in[14], (const float*)d_in[16],
        (const float*)d_in[18], (const float*)d_in[20], Bb);

    slstm_kernel<<<dim3(32, 32), 512, 0, stream>>>(
        (const __hip_bfloat16*)A, Bb, c_prev, n_prev, m_prev, (float*)d_out);
}

// Round 7
// 587.633 us; speedup vs baseline: 1.0616x; 1.0268x over previous
//
#include <hip/hip_runtime.h>
#include <hip/hip_bf16.h>

// sLSTM block, MI355X. One fused bf16 MFMA GEMM
//   P[g] = [x|h] (4096x4096) @ [Wg|Rg]^T (2048x4096), g in {z,i,f,o}
// with gating epilogue fused (LDS exchange of the 4 gate tiles).
// R10 = R9's single-barrier double-buffer schedule (proven)
//     + R8's k-panel workspace layout + conv kernels (proven, 0 conflicts)
//     + R3's 16x16x32 acc[4][4] wave shape (fastest).
//   LDS per buffer: As[4 kc][128 row][16B] (8KB) + Bs[4 kc][256 gr][16B] (16KB).
//   Frag ds_read_b128: 256B contiguous per quarter-wave -> 2 lanes/bank (free).
//   Staging: 24 x 1KB fully-contiguous global loads -> linear LDS dest.
// Workspace (k-panel, 16B chunks of 8 bf16):
//   A_p [512 kc][4096 row][8]  @0      (32MB)
//   W_p [512 kc][8192 grow][8] @32MB   (64MB)   grow = gate*2048 + j
//   Bb  fp32 [4][2048]         @96MB

#define BATCH 4096
#define NHID  2048
#define KDIM  4096
#define NTOT  8388608L   // BATCH*NHID
#define AW_OFS 16777216  // ushort elements from A_p base to W_p base
#define BUFSZ 24576      // one stage buffer: A 8KB + B 16KB (BK=32)

typedef float  f32x4   __attribute__((ext_vector_type(4)));
typedef short  short8  __attribute__((ext_vector_type(8)));
typedef unsigned short ushort8 __attribute__((ext_vector_type(8)));

#define GL_LDS16(gp, lp)                                                      \
    __builtin_amdgcn_global_load_lds(                                         \
        (const __attribute__((address_space(1))) void*)(gp),                  \
        (__attribute__((address_space(3))) void*)(lp), 16, 0, 0)

__device__ __forceinline__ unsigned short f2bf(float f) {
    unsigned u = __float_as_uint(f);
    unsigned r = (u + 0x7fffu + ((u >> 16) & 1u)) >> 16;   // RNE
    return (unsigned short)r;
}

// ---- fp32 -> bf16 k-panel pack of A = [x | h_prev] ------------------------
// Block: 32 rows x 64 k (8 chunks). LDS-transposed so global writes are
// contiguous 512B runs. grid (128 row-tiles, 64 k-tiles) x 256 thr.
__global__ void convA_kernel(const float* __restrict__ x,
                             const float* __restrict__ h,
                             unsigned short* __restrict__ Ap) {
    __shared__ unsigned short tile[8][32][8];
    const int t  = threadIdx.x;
    const int r  = t >> 3, c8 = t & 7;
    const int row = blockIdx.x * 32 + r;
    const int k0  = blockIdx.y * 64;
    const float* src = (blockIdx.y < 32)
        ? (x + (long)row * 2048 + k0 + c8 * 8)
        : (h + (long)row * 2048 + (k0 - 2048) + c8 * 8);
    f32x4 v0 = __builtin_nontemporal_load((const f32x4*)src);
    f32x4 v1 = __builtin_nontemporal_load((const f32x4*)src + 1);
    ushort8 o;
    o[0] = f2bf(v0[0]); o[1] = f2bf(v0[1]); o[2] = f2bf(v0[2]); o[3] = f2bf(v0[3]);
    o[4] = f2bf(v1[0]); o[5] = f2bf(v1[1]); o[6] = f2bf(v1[2]); o[7] = f2bf(v1[3]);
    *(ushort8*)&tile[c8][(r ^ (c8 << 2)) & 31][0] = o;   // XOR-swz: no bank conflict
    __syncthreads();
    const int kcl = t >> 5, rr = t & 31;
    ushort8 w = *(ushort8*)&tile[kcl][(rr ^ (kcl << 2)) & 31][0];
    long dst = ((long)(blockIdx.y * 8 + kcl) * 4096 + blockIdx.x * 32 + rr) * 8;
    __builtin_nontemporal_store(w, (ushort8*)(Ap + dst));
}

// ---- fp32 -> bf16 k-panel pack of W_p ------------------------------------
// z = blockIdx.z: 0..3 = Wzx..Wox (k<2048), 4..7 = Rzh..Roh (k>=2048).
// grid (64 j-tiles of 32, 32 k2-tiles of 64, 8) x 256 thr.
__global__ void convW_kernel(const float* __restrict__ w0, const float* __restrict__ w1,
                             const float* __restrict__ w2, const float* __restrict__ w3,
                             const float* __restrict__ w4, const float* __restrict__ w5,
                             const float* __restrict__ w6, const float* __restrict__ w7,
                             unsigned short* __restrict__ Wp) {
    __shared__ unsigned short tile[8][32][8];
    const int z = blockIdx.z;
    const float* src;
    switch (z) {
        case 0: src = w0; break; case 1: src = w1; break;
        case 2: src = w2; break; case 3: src = w3; break;
        case 4: src = w4; break; case 5: src = w5; break;
        case 6: src = w6; break; default: src = w7; break;
    }
    const int g = z & 3, hf = z >> 2;
    const int t = threadIdx.x;
    const int r = t >> 3, c8 = t & 7;
    const int j  = blockIdx.x * 32 + r;
    const int k2 = blockIdx.y * 64 + c8 * 8;
    const float* p = src + (long)j * 2048 + k2;
    f32x4 v0 = __builtin_nontemporal_load((const f32x4*)p);
    f32x4 v1 = __builtin_nontemporal_load((const f32x4*)p + 1);
    ushort8 o;
    o[0] = f2bf(v0[0]); o[1] = f2bf(v0[1]); o[2] = f2bf(v0[2]); o[3] = f2bf(v0[3]);
    o[4] = f2bf(v1[0]); o[5] = f2bf(v1[1]); o[6] = f2bf(v1[2]); o[7] = f2bf(v1[3]);
    *(ushort8*)&tile[c8][(r ^ (c8 << 2)) & 31][0] = o;
    __syncthreads();
    const int kcl = t >> 5, rr = t & 31;
    ushort8 w = *(ushort8*)&tile[kcl][(rr ^ (kcl << 2)) & 31][0];
    const int kcg = hf * 256 + blockIdx.y * 8 + kcl;
    long dst = ((long)kcg * 8192 + g * 2048 + blockIdx.x * 32 + rr) * 8;
    __builtin_nontemporal_store(w, (ushort8*)(Wp + dst));
}

// ---- combined bias Bb[g][j] = Wg_b[j] + Rg_b[j] ---------------------------
__global__ void bias_kernel(const float* __restrict__ b0, const float* __restrict__ b1,
                            const float* __restrict__ b2, const float* __restrict__ b3,
                            const float* __restrict__ r0, const float* __restrict__ r1,
                            const float* __restrict__ r2, const float* __restrict__ r3,
                            float* __restrict__ Bb) {
    int gid = blockIdx.x * 256 + threadIdx.x;        // 0..8191
    int g = gid >> 11, j = gid & 2047;
    const float *wb, *rb;
    switch (g) {
        case 0: wb = b0; rb = r0; break; case 1: wb = b1; rb = r1; break;
        case 2: wb = b2; rb = r2; break; default: wb = b3; rb = r3; break;
    }
    Bb[gid] = wb[j] + rb[j];
}

// ---- fused GEMM (4 gates) + sLSTM epilogue --------------------------------
// block: 512 threads = 8 waves; wave w: gate = w&3, rowhalf rh = w>>2.
// Each wave computes a 64x64 tile of its gate (4x4 of 16x16x32 MFMA).
// grid: (32 row-tiles of 128, 32 col-tiles of 64); x fastest.
// LDS 48KB = 2 x 24KB buffers:
//   As[kc<4][row<128][16B] @0 (8KB): frag addr = quad*2048+(rh*64+lm)*16+mt*256
//   Bs[kc<4][gr<256][16B] @8K (16KB): gr = gate*64+rr
// Quarter-wave frag reads are 256B contiguous -> 2 lanes/bank (free).
// Staging: 24 x 1KB contiguous loads per K-tile (3 per wave), linear LDS dest.
// Pipeline (single barrier per K-step):
//   iter kt: vmcnt(0) [own tile-kt loads, issued during iter kt-1];
//            s_barrier; issue stage(kt+1) -> other buffer; 8 ds_read, 16 MFMA.
__global__ __launch_bounds__(512, 4) void slstm_kernel(
    const unsigned short* __restrict__ Ap,   // k-panel A; W panels at +AW_OFS
    const float* __restrict__ Bb,            // [4][2048]
    const float* __restrict__ c_prev,
    const float* __restrict__ n_prev,
    const float* __restrict__ m_prev,
    float* __restrict__ out)                 // h | c | n | m
{
    __shared__ uint4 smem4[(2 * BUFSZ) / 16];   // 48 KB -> multi-block/CU
    char* smem = (char*)smem4;

    const int tid  = threadIdx.x;
    const int lane = tid & 63;
    const int wv   = tid >> 6;     // wave id 0..7
    const int gate = wv & 3;
    const int rh   = wv >> 2;      // row half 0/1
    const int lm   = lane & 15;
    const int quad = lane >> 4;

    const int row0 = blockIdx.x * 128;  // batch rows
    const int col0 = blockIdx.y * 64;   // hidden cols

    // fragment ds_read bases (k-chunk = quad)
    const int abase = quad * 2048 + (rh * 64 + lm) * 16;           // + mt*256
    const int bbase = 8192 + quad * 4096 + (gate * 64 + lm) * 16;  // + nt*256

    // staging: 24 x 1KB contiguous loads (ids 0..7 -> As, 8..23 -> Bs);
    // wave w issues ids w*3..w*3+2.
    int gofs[3], strd[3], lofs[3];
#pragma unroll
    for (int t = 0; t < 3; ++t) {
        int id = wv * 3 + t;
        if (id < 8) {
            int kc = id >> 1, half = id & 1;                 // A: kc, row-half
            gofs[t] = (kc * 4096 + row0 + half * 64 + lane) * 8;
            strd[t] = 4 * 4096 * 8;                          // +4 kc per K-tile
            lofs[t] = id * 1024 + lane * 16;
        } else {
            int idb = id - 8;
            int kc = idb >> 2, g = idb & 3;                  // B: kc, gate
            gofs[t] = AW_OFS + (kc * 8192 + g * 2048 + col0 + lane) * 8;
            strd[t] = 4 * 8192 * 8;
            lofs[t] = 8192 + idb * 1024 + lane * 16;
        }
    }

    f32x4 acc[4][4];
#pragma unroll
    for (int mt = 0; mt < 4; ++mt)
#pragma unroll
        for (int nt = 0; nt < 4; ++nt)
#pragma unroll
            for (int r = 0; r < 4; ++r) acc[mt][nt][r] = 0.0f;

    // prologue: stage tile 0 -> buf0; advance offsets to tile 1
#pragma unroll
    for (int t = 0; t < 3; ++t) {
        GL_LDS16(Ap + gofs[t], smem + lofs[t]);
        gofs[t] += strd[t];
    }

    for (int kt = 0; kt < 128; ++kt) {
        // own tile-kt loads were issued during iter kt-1 (or prologue):
        // a full compute phase of slack. Retire them, then rendezvous.
        asm volatile("s_waitcnt vmcnt(0)" ::: "memory");
        __builtin_amdgcn_s_barrier();

        const char* cur = smem + (kt & 1) * BUFSZ;
        char*       wrt = smem + ((kt & 1) ^ 1) * BUFSZ;

        if (kt < 127) {
#pragma unroll
            for (int t = 0; t < 3; ++t) {
                GL_LDS16(Ap + gofs[t], wrt + lofs[t]);
                gofs[t] += strd[t];
            }
        }

        short8 af[4], bf[4];
#pragma unroll
        for (int mt = 0; mt < 4; ++mt)
            af[mt] = *(const short8*)(cur + abase + mt * 256);
#pragma unroll
        for (int nt = 0; nt < 4; ++nt)
            bf[nt] = *(const short8*)(cur + bbase + nt * 256);
#pragma unroll
        for (int mt = 0; mt < 4; ++mt)
#pragma unroll
            for (int nt = 0; nt < 4; ++nt)
                acc[mt][nt] = __builtin_amdgcn_mfma_f32_16x16x32_bf16(
                    af[mt], bf[nt], acc[mt][nt], 0, 0, 0);
    }

    // ---- epilogue: exchange gate tiles through LDS, compute h,c,n,m ----
    float* exch = (float*)smem;   // [2 rh][4 gates][16 rows][65] floats (33.3KB)
#pragma unroll
    for (int mt = 0; mt < 4; ++mt) {
        __syncthreads();
#pragma unroll
        for (int nt = 0; nt < 4; ++nt)
#pragma unroll
            for (int r = 0; r < 4; ++r)
                exch[((rh * 4 + gate) * 16 + quad * 4 + r) * 65 + nt * 16 + lm] =
                    acc[mt][nt][r];
        __syncthreads();
#pragma unroll
        for (int q = 0; q < 4; ++q) {
            int e   = q * 512 + tid;          // 0..2047
            int erh = e >> 10, row = (e >> 6) & 15, col = e & 63;
            int R = row0 + erh * 64 + mt * 16 + row;
            int C = col0 + col;
            long idx = (long)R * NHID + C;
            float zp = exch[((erh * 4 + 0) * 16 + row) * 65 + col] + Bb[C];
            float ip = exch[((erh * 4 + 1) * 16 + row) * 65 + col] + Bb[2048 + C];
            float fp = exch[((erh * 4 + 2) * 16 + row) * 65 + col] + Bb[4096 + C];
            float op = exch[((erh * 4 + 3) * 16 + row) * 65 + col] + Bb[6144 + C];
            float cp = __builtin_nontemporal_load(c_prev + idx);
            float np = __builtin_nontemporal_load(n_prev + idx);
            float mp = __builtin_nontemporal_load(m_prev + idx);
            float z  = tanhf(zp);
            float o  = 1.0f / (1.0f + __expf(-op));
            float mm = fmaxf(fp + mp, ip);
            float ih = __expf(ip - mm);
            float fh = __expf(fp + mp - mm);
            float cc = fh * cp + ih * z;
            float nn = fh * np + ih;
            float hh = o * cc / nn;
            __builtin_nontemporal_store(hh, out + idx);
            __builtin_nontemporal_store(cc, out + NTOT + idx);
            __builtin_nontemporal_store(nn, out + 2 * NTOT + idx);
            __builtin_nontemporal_store(mm, out + 3 * NTOT + idx);
        }
    }
}

extern "C" void kernel_launch(void* const* d_in, const int* in_sizes, int n_in,
                              void* d_out, int out_size, void* d_ws, size_t ws_size,
                              hipStream_t stream) {
    const float* x      = (const float*)d_in[0];
    const float* h_prev = (const float*)d_in[1];
    const float* c_prev = (const float*)d_in[2];
    const float* n_prev = (const float*)d_in[3];
    const float* m_prev = (const float*)d_in[4];
    unsigned short* Ap = (unsigned short*)d_ws;                          // 32 MB
    unsigned short* Wp = (unsigned short*)((char*)d_ws + 33554432);      // 64 MB
    float*          Bb = (float*)((char*)d_ws + 100663296);              // 32 KB

    convA_kernel<<<dim3(128, 64), 256, 0, stream>>>(x, h_prev, Ap);
    convW_kernel<<<dim3(64, 32, 8), 256, 0, stream>>>(
        (const float*)d_in[5], (const float*)d_in[7], (const float*)d_in[9],
        (const float*)d_in[11], (const float*)d_in[13], (const float*)d_in[15],
        (const float*)d_in[17], (const float*)d_in[19], Wp);
    bias_kernel<<<32, 256, 0, stream>>>(
        (const float*)d_in[6], (const float*)d_in[8], (const float*)d_in[10],
        (const float*)d_in[12], (const float*)d_in[14], (const float*)d_in[16],
        (const float*)d_in[18], (const float*)d_in[20], Bb);

    slstm_kernel<<<dim3(32, 32), 512, 0, stream>>>(
        Ap, Bb, c_prev, n_prev, m_prev, (float*)d_out);
}